// Round 5
// baseline (366.339 us; speedup 1.0000x reference)
//
#include <hip/hip_runtime.h>
#include <stdint.h>

// ---------------------------------------------------------------------------
// Compile-time tables + fragment-packed bf16 constant matrices for
// MFMA 32x32x16 bf16.  Frag layout (used as A operand): lane l holds
// T[k = ks*16 + (l>>5)*8 + j][n = ntile*32 + (l&31)], j=0..7 packed as 4
// dwords (lo16 = even j).  Because A-frag and B-frag lane layouts are
// mutual transposes, this same table is the A-frag of T^T.
// SYN = Y'  [48 (36 real) x 160 (144 real grid pts)]
// ANA = Yw' [144 x 64 (36 real coeffs)]
// ---------------------------------------------------------------------------
namespace ct {

constexpr double PI_ = 3.14159265358979323846;

constexpr double csqrt(double x) {
  double g = x > 1.0 ? x : 1.0;
  for (int i = 0; i < 40; ++i) g = 0.5 * (g + x / g);
  return g;
}
constexpr double ccos(double x) {  // |x| <= pi
  double x2 = x * x, t = 1.0, s = 1.0;
  for (int k = 1; k <= 16; ++k) { t *= -x2 / ((2.0 * k - 1.0) * (2.0 * k)); s += t; }
  return s;
}
constexpr double csin(double x) {  // |x| <= pi
  double x2 = x * x, t = x, s = x;
  for (int k = 1; k <= 16; ++k) { t *= -x2 / ((2.0 * k) * (2.0 * k + 1.0)); s += t; }
  return s;
}

struct GL { double x[12]; double w[12]; };

constexpr GL gl12() {
  GL g{};
  for (int i = 0; i < 12; ++i) {
    double x = ccos(PI_ * (i + 0.75) / 12.5);
    for (int it = 0; it < 50; ++it) {
      double p0 = 1.0, p1 = x;
      for (int k = 2; k <= 12; ++k) { double pk = ((2.0 * k - 1.0) * x * p1 - (k - 1.0) * p0) / k; p0 = p1; p1 = pk; }
      double dp = 12.0 * (x * p1 - p0) / (x * x - 1.0);
      x -= p1 / dp;
    }
    double p0 = 1.0, p1 = x;
    for (int k = 2; k <= 12; ++k) { double pk = ((2.0 * k - 1.0) * x * p1 - (k - 1.0) * p0) / k; p0 = p1; p1 = pk; }
    double dp = 12.0 * (x * p1 - p0) / (x * x - 1.0);
    g.x[i] = x;
    g.w[i] = 2.0 / ((1.0 - x * x) * dp * dp);
  }
  return g;
}

struct Tab {
  double PA[12][36];   // Pbar_l^{|m|}(x_b) by SH index k
  double PB[12][36];   // PA * wq[b] * (2*pi/12)
  double ANG[12][36];  // angular factor at alpha_a for SH index k
};

constexpr Tab make_tab() {
  Tab t{};
  GL g = gl12();
  for (int b = 0; b < 12; ++b) {
    double x = g.x[b];
    double s = csqrt(1.0 - x * x);
    double P[6][6] = {};
    P[0][0] = csqrt(1.0 / (4.0 * PI_));
    for (int m = 1; m <= 5; ++m) P[m][m] = csqrt((2.0 * m + 1.0) / (2.0 * m)) * s * P[m - 1][m - 1];
    for (int m = 0; m < 5; ++m)  P[m + 1][m] = csqrt(2.0 * m + 3.0) * x * P[m][m];
    for (int m = 0; m <= 5; ++m)
      for (int l = m + 2; l <= 5; ++l) {
        double aa = csqrt((4.0 * l * l - 1.0) / (double)(l * l - m * m));
        double bb = csqrt(((l - 1.0) * (l - 1.0) - (double)(m * m)) / (4.0 * (l - 1.0) * (l - 1.0) - 1.0));
        P[l][m] = aa * (x * P[l - 1][m] - bb * P[l - 2][m]);
      }
    for (int l = 0; l <= 5; ++l)
      for (int m = -l; m <= l; ++m) {
        int k = l * l + l + m, am = m < 0 ? -m : m;
        t.PA[b][k] = P[l][am];
        t.PB[b][k] = P[l][am] * g.w[b] * (2.0 * PI_ / 12.0);
      }
  }
  double r2 = csqrt(2.0);
  for (int a = 0; a < 12; ++a)
    for (int l = 0; l <= 5; ++l)
      for (int m = -l; m <= l; ++m) {
        int k = l * l + l + m, am = m < 0 ? -m : m;
        double v = 1.0;
        if (m != 0) {
          int qq = (am * a) % 12;  // exact angle reduction: angle = 2*pi*qq/12
          double ang = 2.0 * PI_ * qq / 12.0;
          if (ang > PI_) ang -= 2.0 * PI_;
          v = (m > 0) ? r2 * ccos(ang) : r2 * csin(ang);
        }
        t.ANG[a][k] = v;
      }
  return t;
}

constexpr Tab TD = make_tab();

// float -> bf16 bits (round-to-nearest-even), pure-arithmetic constexpr.
constexpr unsigned f2bf(double x) {
  if (x == 0.0) return 0u;
  unsigned s = 0u; double a = x;
  if (a < 0.0) { s = 0x8000u; a = -a; }
  int e = 127;
  while (a >= 2.0) { a *= 0.5; ++e; }
  while (a < 1.0)  { a *= 2.0; --e; }
  double md = (a - 1.0) * 128.0;
  int mi = (int)md;
  double fr = md - mi;
  if (fr > 0.5 || (fr == 0.5 && (mi & 1))) ++mi;
  if (mi == 128) { mi = 0; ++e; }
  return s | ((unsigned)e << 7) | (unsigned)mi;
}

constexpr double syn_val(int k, int n) {  // Y'[k][n], n = b*12 + a
  if (k >= 36 || n >= 144) return 0.0;
  int b = n / 12, a = n % 12;
  return TD.PA[b][k] * TD.ANG[a][k];
}
constexpr double ana_val(int kp, int np) {  // Yw'[kp][np], kp = b*12 + a
  if (kp >= 144 || np >= 36) return 0.0;
  int b = kp / 12, a = kp % 12;
  return TD.PB[b][np] * TD.ANG[a][np];
}

struct alignas(16) Syn32 { unsigned v[3 * 5 * 64 * 4]; };  // 15360 B (960 uint4)
struct alignas(16) Ana32 { unsigned v[9 * 2 * 64 * 4]; };  // 18432 B (1152 uint4)

constexpr Syn32 make_syn32() {
  Syn32 F{};
  for (int ks = 0; ks < 3; ++ks)
    for (int nt = 0; nt < 5; ++nt)
      for (int lane = 0; lane < 64; ++lane)
        for (int jp = 0; jp < 4; ++jp) {
          int h = lane >> 5, n = nt * 32 + (lane & 31);
          int k0 = ks * 16 + h * 8 + jp * 2;
          F.v[((ks * 5 + nt) * 64 + lane) * 4 + jp] =
              f2bf(syn_val(k0, n)) | (f2bf(syn_val(k0 + 1, n)) << 16);
        }
  return F;
}
constexpr Ana32 make_ana32() {
  Ana32 F{};
  for (int ks = 0; ks < 9; ++ks)
    for (int nt = 0; nt < 2; ++nt)
      for (int lane = 0; lane < 64; ++lane)
        for (int jp = 0; jp < 4; ++jp) {
          int h = lane >> 5, n = nt * 32 + (lane & 31);
          int k0 = ks * 16 + h * 8 + jp * 2;
          F.v[((ks * 2 + nt) * 64 + lane) * 4 + jp] =
              f2bf(ana_val(k0, n)) | (f2bf(ana_val(k0 + 1, n)) << 16);
        }
  return F;
}

}  // namespace ct

__device__ constexpr ct::Syn32 SYNB = ct::make_syn32();
__device__ constexpr ct::Ana32 ANAB = ct::make_ana32();

typedef __attribute__((ext_vector_type(8))) short short8;
typedef __attribute__((ext_vector_type(16))) float f32x16;

union S8 { short8 s; unsigned u[4]; uint2 u2[2]; };

__device__ __forceinline__ unsigned short bfr(float x) {
  return (unsigned short)((__float_as_uint(x) + 0x8000u) >> 16);
}
__device__ __forceinline__ unsigned pk2(float x, float y) {
  return (unsigned)bfr(x) | ((unsigned)bfr(y) << 16);
}

// 16-B fragment read (ds_read_b128 when p points into LDS).
__device__ __forceinline__ short8 fr16(const uint4* p) {
  uint4 t = *p; S8 r; r.u[0] = t.x; r.u[1] = t.y; r.u[2] = t.z; r.u[3] = t.w;
  return r.s;
}

// Build one B-frag (K-chunk of 16) from MFMA C-layout values via half-wave
// register exchange.  Input: 4 bf16x2 dwords P0,P1 (reg group g=2q) and
// Q0,Q1 (reg group g=2q+1) of the C-layout accumulator.  C-layout reg r=4g+i
// on lane-half h' holds row offset o = i + 8g + 4h'; the B-frag for lane-half
// h needs o = 16q + 8h + j (j=0..7).  One v_permlane32_swap per dword pair
// delivers both needed dwords (own-half keep + cross-half exchange).
__device__ __forceinline__ S8 mkfrag(unsigned P0, unsigned P1, unsigned Q0, unsigned Q1) {
  auto r0 = __builtin_amdgcn_permlane32_swap((int)P0, (int)Q0, false, false);
  auto r1 = __builtin_amdgcn_permlane32_swap((int)P1, (int)Q1, false, false);
  S8 f;
  f.u[0] = (unsigned)r0[0];  // j0,j1
  f.u[1] = (unsigned)r1[0];  // j2,j3
  f.u[2] = (unsigned)r0[1];  // j4,j5
  f.u[3] = (unsigned)r1[1];  // j6,j7
  return f;
}

#define Z16 {0.f,0.f,0.f,0.f,0.f,0.f,0.f,0.f,0.f,0.f,0.f,0.f,0.f,0.f,0.f,0.f}

// All four GEMMs computed operand-swapped (D = T^T * X^T): the constant SH
// table is the A operand, so every lane owns one CHANNEL row of each result
// and all inter-GEMM transposes happen in-register (mkfrag).
// Round-5 structure: the two phase loops are #pragma unroll 1 so the LDS
// table-fragment reads (33 x ds_read_b128 per phase = 132 VGPRs if hoisted)
// CANNOT be hoisted across iterations -- rounds 2-4 showed that hoisting,
// not the persistent state, was the spill source (~280 MB scratch traffic).
// Inner ks/q loops stay unrolled so all vector indices are compile-time.
__global__ __launch_bounds__(256, 2)
void gaunt32_kernel(const float* __restrict__ feat,
                    const float* __restrict__ atype,
                    const float* __restrict__ wts,
                    float* __restrict__ out) {
  __shared__ uint4 TAB[2112];  // 33792 B: SYN frags [0,960), ANA frags [960,2112)

  const int tid = threadIdx.x;
  const int lane = tid & 63;
  const int m = lane & 31, h = lane >> 5;
  const int mtile = blockIdx.x * 4 + (tid >> 6);
  const int rowbase = mtile * 32;
  const int atom = mtile >> 2;         // 4 tiles per atom
  const int chb = (mtile & 3) * 32;    // channel base within atom

  // ---- stage constant tables: global -> LDS (L2-resident across blocks) ----
  {
    const uint4* s4 = reinterpret_cast<const uint4*>(SYNB.v);
    const uint4* a4 = reinterpret_cast<const uint4*>(ANAB.v);
#pragma unroll
    for (int i = 0; i < 4; ++i) {
      int idx = tid + 256 * i;
      if (idx < 960) TAB[idx] = s4[idx];
    }
#pragma unroll
    for (int i = 0; i < 5; ++i) {
      int idx = tid + 256 * i;
      if (idx < 1152) TAB[960 + idx] = a4[idx];
    }
  }

  const uint4* syn = TAB;        // frag (ks,nt): syn[(ks*5+nt)*64 + lane]
  const uint4* ana = TAB + 960;  // frag (ks,nt): ana[(ks*2+nt)*64 + lane]

  // ---- B-frag of c0^T straight from global (lane m holds row m's coeffs) ----
  const float* fr = feat + (size_t)(rowbase + m) * 36;
  S8 af[3];
  {
    float4 a = *reinterpret_cast<const float4*>(fr + h * 8);
    float4 b = *reinterpret_cast<const float4*>(fr + h * 8 + 4);
    af[0].u[0] = pk2(a.x, a.y); af[0].u[1] = pk2(a.z, a.w);
    af[0].u[2] = pk2(b.x, b.y); af[0].u[3] = pk2(b.z, b.w);
    a = *reinterpret_cast<const float4*>(fr + 16 + h * 8);
    b = *reinterpret_cast<const float4*>(fr + 20 + h * 8);
    af[1].u[0] = pk2(a.x, a.y); af[1].u[1] = pk2(a.z, a.w);
    af[1].u[2] = pk2(b.x, b.y); af[1].u[3] = pk2(b.z, b.w);
    af[2].u[0] = 0; af[2].u[1] = 0; af[2].u[2] = 0; af[2].u[3] = 0;
    if (h == 0) {  // k = 32..35 real; 36..47 zero (table rows >=36 are zero)
      a = *reinterpret_cast<const float4*>(fr + 32);
      af[2].u[0] = pk2(a.x, a.y); af[2].u[1] = pk2(a.z, a.w);
    }
  }

  // ---- wn[nu][l] for this lane's channel (atype row is wave-uniform) ----
  float wnv[3][6];
  {
    const float* ab = atype + atom * 10;
    float at_[10];
#pragma unroll
    for (int e = 0; e < 10; ++e) at_[e] = ab[e];
    const float* wb = wts + (size_t)(chb + m) * 6;
#pragma unroll
    for (int nu = 0; nu < 3; ++nu) {
#pragma unroll
      for (int l = 0; l < 6; ++l) wnv[nu][l] = 0.f;
#pragma unroll
      for (int e = 0; e < 10; ++e) {
        const float* p = wb + (size_t)(nu * 10 + e) * 768;
        float2 x = *reinterpret_cast<const float2*>(p);
        float2 y = *reinterpret_cast<const float2*>(p + 2);
        float2 z = *reinterpret_cast<const float2*>(p + 4);
        wnv[nu][0] += at_[e] * x.x; wnv[nu][1] += at_[e] * x.y;
        wnv[nu][2] += at_[e] * y.x; wnv[nu][3] += at_[e] * y.y;
        wnv[nu][4] += at_[e] * z.x; wnv[nu][5] += at_[e] * z.y;
      }
    }
  }

  // l-index of output col c = 8g+4h+i:  LC0t for h=0, LC1t for h=1.
  constexpr int LC0t[4][4] = {{0,1,1,1},{2,3,3,3},{4,4,4,4},{4,5,5,5}};  // l(8g+i)
  constexpr int LC1t[4][4] = {{2,2,2,2},{3,3,3,3},{4,4,4,4},{5,5,5,5}};  // l(8g+4+i)

  // ---- ovg/ov5 accumulators initialized with the w0*c0 term (fp32 c0) ----
  float ovg[4][4];
  float ov5[4];
  {
#pragma unroll
    for (int g = 0; g < 4; ++g) {
      float4 c = *reinterpret_cast<const float4*>(fr + 8 * g + 4 * h);
      const float* cp = reinterpret_cast<const float*>(&c);
#pragma unroll
      for (int i = 0; i < 4; ++i) {
        const float w0 = h ? wnv[0][LC1t[g][i]] : wnv[0][LC0t[g][i]];
        ovg[g][i] = w0 * cp[i];
      }
    }
    float4 c5 = {0.f, 0.f, 0.f, 0.f};
    if (h == 0) c5 = *reinterpret_cast<const float4*>(fr + 32);
    const float* cp = reinterpret_cast<const float*>(&c5);
#pragma unroll
    for (int i = 0; i < 4; ++i) ov5[i] = wnv[0][5] * cp[i];
  }
  // wnv[0] is now dead.

  __syncthreads();  // tables ready (once per block)

  // ---- phase A: GEMM1 (f^T = Y'^T c0^T) fused with g1 = f*f frag build and
  //      GEMM2 (prod1^T = Yw'^T g1^T).  unroll 1: runtime mt keeps the 7
  //      ds_read_b128/iter from being hoisted (spill control). ----
  f32x16 p1[2]; p1[0] = (f32x16)Z16; p1[1] = (f32x16)Z16;
#pragma unroll 1
  for (int mt = 0; mt < 5; ++mt) {
    f32x16 a1 = Z16;
#pragma unroll
    for (int ks = 0; ks < 3; ++ks)
      a1 = __builtin_amdgcn_mfma_f32_32x32x16_bf16(fr16(syn + (ks * 5 + mt) * 64 + lane),
                                                   af[ks].s, a1, 0, 0, 0);
#pragma unroll
    for (int q = 0; q < 2; ++q) {
      if (q == 0 || mt < 4) {  // ksg = 2*mt+q < 9
        const int ksg = 2 * mt + q;
        S8 fb = mkfrag(pk2(a1[8*q+0]*a1[8*q+0], a1[8*q+1]*a1[8*q+1]),
                       pk2(a1[8*q+2]*a1[8*q+2], a1[8*q+3]*a1[8*q+3]),
                       pk2(a1[8*q+4]*a1[8*q+4], a1[8*q+5]*a1[8*q+5]),
                       pk2(a1[8*q+6]*a1[8*q+6], a1[8*q+7]*a1[8*q+7]));
        p1[0] = __builtin_amdgcn_mfma_f32_32x32x16_bf16(fr16(ana + (ksg * 2 + 0) * 64 + lane),
                                                        fb.s, p1[0], 0, 0, 0);
        p1[1] = __builtin_amdgcn_mfma_f32_32x32x16_bf16(fr16(ana + (ksg * 2 + 1) * 64 + lane),
                                                        fb.s, p1[1], 0, 0, 0);
      }
    }
  }

  // ---- fold w1*prod1 into ovg/ov5, then build b3 frags; p1 dies here ----
#pragma unroll
  for (int g = 0; g < 4; ++g)
#pragma unroll
    for (int i = 0; i < 4; ++i) {
      const float w1 = h ? wnv[1][LC1t[g][i]] : wnv[1][LC0t[g][i]];
      ovg[g][i] += w1 * p1[0][4 * g + i];
    }
#pragma unroll
  for (int i = 0; i < 4; ++i) ov5[i] += wnv[1][5] * p1[1][i];
  // wnv[1] dead; only wnv[2][0..5] stays live through phase B.

  // ---- B-frags of prod1^T (K=48; SH 36..47 are exact zeros from N-pad) ----
  S8 b3[3];
  b3[0] = mkfrag(pk2(p1[0][0],  p1[0][1]),  pk2(p1[0][2],  p1[0][3]),
                 pk2(p1[0][4],  p1[0][5]),  pk2(p1[0][6],  p1[0][7]));
  b3[1] = mkfrag(pk2(p1[0][8],  p1[0][9]),  pk2(p1[0][10], p1[0][11]),
                 pk2(p1[0][12], p1[0][13]), pk2(p1[0][14], p1[0][15]));
  b3[2] = mkfrag(pk2(p1[1][0],  p1[1][1]),  pk2(p1[1][2],  p1[1][3]),
                 pk2(p1[1][4],  p1[1][5]),  pk2(p1[1][6],  p1[1][7]));

  // ---- phase B: recompute f (GEMM1-bis) + GEMM3 (f2^T = Y'^T prod1^T),
  //      g2 = f2*f (both f32), GEMM4 (prod2^T = Yw'^T g2^T).
  //      Each SYN frag read feeds TWO MFMAs.  unroll 1 as phase A. ----
  f32x16 p2[2]; p2[0] = (f32x16)Z16; p2[1] = (f32x16)Z16;
#pragma unroll 1
  for (int mt = 0; mt < 5; ++mt) {
    f32x16 a1 = Z16, a3 = Z16;
#pragma unroll
    for (int ks = 0; ks < 3; ++ks) {
      short8 y = fr16(syn + (ks * 5 + mt) * 64 + lane);
      a1 = __builtin_amdgcn_mfma_f32_32x32x16_bf16(y, af[ks].s, a1, 0, 0, 0);
      a3 = __builtin_amdgcn_mfma_f32_32x32x16_bf16(y, b3[ks].s, a3, 0, 0, 0);
    }
#pragma unroll
    for (int q = 0; q < 2; ++q) {
      if (q == 0 || mt < 4) {  // ksg = 2*mt+q < 9
        const int ksg = 2 * mt + q;
        S8 gb = mkfrag(pk2(a3[8*q+0]*a1[8*q+0], a3[8*q+1]*a1[8*q+1]),
                       pk2(a3[8*q+2]*a1[8*q+2], a3[8*q+3]*a1[8*q+3]),
                       pk2(a3[8*q+4]*a1[8*q+4], a3[8*q+5]*a1[8*q+5]),
                       pk2(a3[8*q+6]*a1[8*q+6], a3[8*q+7]*a1[8*q+7]));
        p2[0] = __builtin_amdgcn_mfma_f32_32x32x16_bf16(fr16(ana + (ksg * 2 + 0) * 64 + lane),
                                                        gb.s, p2[0], 0, 0, 0);
        p2[1] = __builtin_amdgcn_mfma_f32_32x32x16_bf16(fr16(ana + (ksg * 2 + 1) * 64 + lane),
                                                        gb.s, p2[1], 0, 0, 0);
      }
    }
  }

  // ---- final fold (w2*prod2) + store ----
  float* o0 = out + (size_t)(rowbase + m) * 36;
#pragma unroll
  for (int g = 0; g < 4; ++g) {
    float ov[4];
#pragma unroll
    for (int i = 0; i < 4; ++i) {
      const float w2 = h ? wnv[2][LC1t[g][i]] : wnv[2][LC0t[g][i]];
      ov[i] = ovg[g][i] + w2 * p2[0][4 * g + i];
    }
    float4 o4 = {ov[0], ov[1], ov[2], ov[3]};
    *reinterpret_cast<float4*>(o0 + 8 * g + 4 * h) = o4;
  }
  if (h == 0) {  // SH 32..35 (l=5), ntile-1 accumulator regs 0..3
    float ov[4];
#pragma unroll
    for (int i = 0; i < 4; ++i) ov[i] = ov5[i] + wnv[2][5] * p2[1][i];
    float4 o4 = {ov[0], ov[1], ov[2], ov[3]};
    *reinterpret_cast<float4*>(o0 + 32) = o4;
  }
}

extern "C" void kernel_launch(void* const* d_in, const int* in_sizes, int n_in,
                              void* d_out, int out_size, void* d_ws, size_t ws_size,
                              hipStream_t stream) {
  const float* feat = (const float*)d_in[0];   // [4096,128,36] f32
  const float* atype = (const float*)d_in[1];  // [4096,10] f32
  const float* wts = (const float*)d_in[2];    // [3,10,128,6] f32
  float* out = (float*)d_out;                  // [4096,128,36] f32
  (void)in_sizes; (void)n_in; (void)out_size; (void)d_ws; (void)ws_size;

  // 524288 rows / 32 per wave = 16384 tiles; 4 waves per block -> 4096 blocks.
  gaunt32_kernel<<<4096, 256, 0, stream>>>(feat, atype, wts, out);
}

// Round 6
// 235.676 us; speedup vs baseline: 1.5544x; 1.5544x over previous
//
#include <hip/hip_runtime.h>
#include <stdint.h>

// ---------------------------------------------------------------------------
// Compile-time tables + fragment-packed bf16 constant matrices for
// MFMA 32x32x16 bf16.  Frag layout (used as A operand): lane l holds
// T[k = ks*16 + (l>>5)*8 + j][n = ntile*32 + (l&31)], j=0..7 packed as 4
// dwords (lo16 = even j).  Because A-frag and B-frag lane layouts are
// mutual transposes, this same table is the A-frag of T^T.
// SYN = Y'  [48 (36 real) x 160 (144 real grid pts)]
// ANA = Yw' [144 x 64 (36 real coeffs)]
// ---------------------------------------------------------------------------
namespace ct {

constexpr double PI_ = 3.14159265358979323846;

constexpr double csqrt(double x) {
  double g = x > 1.0 ? x : 1.0;
  for (int i = 0; i < 40; ++i) g = 0.5 * (g + x / g);
  return g;
}
constexpr double ccos(double x) {  // |x| <= pi
  double x2 = x * x, t = 1.0, s = 1.0;
  for (int k = 1; k <= 16; ++k) { t *= -x2 / ((2.0 * k - 1.0) * (2.0 * k)); s += t; }
  return s;
}
constexpr double csin(double x) {  // |x| <= pi
  double x2 = x * x, t = x, s = x;
  for (int k = 1; k <= 16; ++k) { t *= -x2 / ((2.0 * k) * (2.0 * k + 1.0)); s += t; }
  return s;
}

struct GL { double x[12]; double w[12]; };

constexpr GL gl12() {
  GL g{};
  for (int i = 0; i < 12; ++i) {
    double x = ccos(PI_ * (i + 0.75) / 12.5);
    for (int it = 0; it < 50; ++it) {
      double p0 = 1.0, p1 = x;
      for (int k = 2; k <= 12; ++k) { double pk = ((2.0 * k - 1.0) * x * p1 - (k - 1.0) * p0) / k; p0 = p1; p1 = pk; }
      double dp = 12.0 * (x * p1 - p0) / (x * x - 1.0);
      x -= p1 / dp;
    }
    double p0 = 1.0, p1 = x;
    for (int k = 2; k <= 12; ++k) { double pk = ((2.0 * k - 1.0) * x * p1 - (k - 1.0) * p0) / k; p0 = p1; p1 = pk; }
    double dp = 12.0 * (x * p1 - p0) / (x * x - 1.0);
    g.x[i] = x;
    g.w[i] = 2.0 / ((1.0 - x * x) * dp * dp);
  }
  return g;
}

struct Tab {
  double PA[12][36];   // Pbar_l^{|m|}(x_b) by SH index k
  double PB[12][36];   // PA * wq[b] * (2*pi/12)
  double ANG[12][36];  // angular factor at alpha_a for SH index k
};

constexpr Tab make_tab() {
  Tab t{};
  GL g = gl12();
  for (int b = 0; b < 12; ++b) {
    double x = g.x[b];
    double s = csqrt(1.0 - x * x);
    double P[6][6] = {};
    P[0][0] = csqrt(1.0 / (4.0 * PI_));
    for (int m = 1; m <= 5; ++m) P[m][m] = csqrt((2.0 * m + 1.0) / (2.0 * m)) * s * P[m - 1][m - 1];
    for (int m = 0; m < 5; ++m)  P[m + 1][m] = csqrt(2.0 * m + 3.0) * x * P[m][m];
    for (int m = 0; m <= 5; ++m)
      for (int l = m + 2; l <= 5; ++l) {
        double aa = csqrt((4.0 * l * l - 1.0) / (double)(l * l - m * m));
        double bb = csqrt(((l - 1.0) * (l - 1.0) - (double)(m * m)) / (4.0 * (l - 1.0) * (l - 1.0) - 1.0));
        P[l][m] = aa * (x * P[l - 1][m] - bb * P[l - 2][m]);
      }
    for (int l = 0; l <= 5; ++l)
      for (int m = -l; m <= l; ++m) {
        int k = l * l + l + m, am = m < 0 ? -m : m;
        t.PA[b][k] = P[l][am];
        t.PB[b][k] = P[l][am] * g.w[b] * (2.0 * PI_ / 12.0);
      }
  }
  double r2 = csqrt(2.0);
  for (int a = 0; a < 12; ++a)
    for (int l = 0; l <= 5; ++l)
      for (int m = -l; m <= l; ++m) {
        int k = l * l + l + m, am = m < 0 ? -m : m;
        double v = 1.0;
        if (m != 0) {
          int qq = (am * a) % 12;  // exact angle reduction: angle = 2*pi*qq/12
          double ang = 2.0 * PI_ * qq / 12.0;
          if (ang > PI_) ang -= 2.0 * PI_;
          v = (m > 0) ? r2 * ccos(ang) : r2 * csin(ang);
        }
        t.ANG[a][k] = v;
      }
  return t;
}

constexpr Tab TD = make_tab();

// float -> bf16 bits (round-to-nearest-even), pure-arithmetic constexpr.
constexpr unsigned f2bf(double x) {
  if (x == 0.0) return 0u;
  unsigned s = 0u; double a = x;
  if (a < 0.0) { s = 0x8000u; a = -a; }
  int e = 127;
  while (a >= 2.0) { a *= 0.5; ++e; }
  while (a < 1.0)  { a *= 2.0; --e; }
  double md = (a - 1.0) * 128.0;
  int mi = (int)md;
  double fr = md - mi;
  if (fr > 0.5 || (fr == 0.5 && (mi & 1))) ++mi;
  if (mi == 128) { mi = 0; ++e; }
  return s | ((unsigned)e << 7) | (unsigned)mi;
}

constexpr double syn_val(int k, int n) {  // Y'[k][n], n = b*12 + a
  if (k >= 36 || n >= 144) return 0.0;
  int b = n / 12, a = n % 12;
  return TD.PA[b][k] * TD.ANG[a][k];
}
constexpr double ana_val(int kp, int np) {  // Yw'[kp][np], kp = b*12 + a
  if (kp >= 144 || np >= 36) return 0.0;
  int b = kp / 12, a = kp % 12;
  return TD.PB[b][np] * TD.ANG[a][np];
}

struct alignas(16) Syn32 { unsigned v[3 * 5 * 64 * 4]; };  // 15360 B (960 uint4)
struct alignas(16) Ana32 { unsigned v[9 * 2 * 64 * 4]; };  // 18432 B (1152 uint4)

constexpr Syn32 make_syn32() {
  Syn32 F{};
  for (int ks = 0; ks < 3; ++ks)
    for (int nt = 0; nt < 5; ++nt)
      for (int lane = 0; lane < 64; ++lane)
        for (int jp = 0; jp < 4; ++jp) {
          int h = lane >> 5, n = nt * 32 + (lane & 31);
          int k0 = ks * 16 + h * 8 + jp * 2;
          F.v[((ks * 5 + nt) * 64 + lane) * 4 + jp] =
              f2bf(syn_val(k0, n)) | (f2bf(syn_val(k0 + 1, n)) << 16);
        }
  return F;
}
constexpr Ana32 make_ana32() {
  Ana32 F{};
  for (int ks = 0; ks < 9; ++ks)
    for (int nt = 0; nt < 2; ++nt)
      for (int lane = 0; lane < 64; ++lane)
        for (int jp = 0; jp < 4; ++jp) {
          int h = lane >> 5, n = nt * 32 + (lane & 31);
          int k0 = ks * 16 + h * 8 + jp * 2;
          F.v[((ks * 2 + nt) * 64 + lane) * 4 + jp] =
              f2bf(ana_val(k0, n)) | (f2bf(ana_val(k0 + 1, n)) << 16);
        }
  return F;
}

}  // namespace ct

__device__ constexpr ct::Syn32 SYNB = ct::make_syn32();
__device__ constexpr ct::Ana32 ANAB = ct::make_ana32();

typedef __attribute__((ext_vector_type(8))) short short8;
typedef __attribute__((ext_vector_type(16))) float f32x16;

union S8 { short8 s; unsigned u[4]; uint2 u2[2]; };

__device__ __forceinline__ unsigned short bfr(float x) {
  return (unsigned short)((__float_as_uint(x) + 0x8000u) >> 16);
}
__device__ __forceinline__ unsigned pk2(float x, float y) {
  return (unsigned)bfr(x) | ((unsigned)bfr(y) << 16);
}

// 16-B fragment read (ds_read_b128 when p points into LDS).
__device__ __forceinline__ short8 fr16(const uint4* p) {
  uint4 t = *p; S8 r; r.u[0] = t.x; r.u[1] = t.y; r.u[2] = t.z; r.u[3] = t.w;
  return r.s;
}

// Build one B-frag (K-chunk of 16) from MFMA C-layout values via half-wave
// register exchange.  Input: 4 bf16x2 dwords P0,P1 (reg group g=2q) and
// Q0,Q1 (reg group g=2q+1) of the C-layout accumulator.  C-layout reg r=4g+i
// on lane-half h' holds row offset o = i + 8g + 4h'; the B-frag for lane-half
// h needs o = 16q + 8h + j (j=0..7).  One v_permlane32_swap per dword pair
// delivers both needed dwords (own-half keep + cross-half exchange).
__device__ __forceinline__ S8 mkfrag(unsigned P0, unsigned P1, unsigned Q0, unsigned Q1) {
  auto r0 = __builtin_amdgcn_permlane32_swap((int)P0, (int)Q0, false, false);
  auto r1 = __builtin_amdgcn_permlane32_swap((int)P1, (int)Q1, false, false);
  S8 f;
  f.u[0] = (unsigned)r0[0];  // j0,j1
  f.u[1] = (unsigned)r1[0];  // j2,j3
  f.u[2] = (unsigned)r0[1];  // j4,j5
  f.u[3] = (unsigned)r1[1];  // j6,j7
  return f;
}

#define Z16 {0.f,0.f,0.f,0.f,0.f,0.f,0.f,0.f,0.f,0.f,0.f,0.f,0.f,0.f,0.f,0.f}

// All four GEMMs computed operand-swapped (D = T^T * X^T): the constant SH
// table is the A operand, so every lane owns one CHANNEL row of each result
// and all inter-GEMM transposes happen in-register (mkfrag).
// Round-6: identical to round 4 except __launch_bounds__(256,1).
// Rounds 1-5 showed the allocator splits the unified register file in half
// (arch VGPR cap = total/2: (256,3)->84, (256,2)->128) and the VALU-visible
// live set (~200: packs/permlanes/folds) never fit, spilling ~280 MB of
// scratch per dispatch.  (256,1) raises the cap to 512 -> arch half 256,
// which covers the live set with margin.  Occupancy stays ~2 waves/SIMD
// (register-limited), but the scratch round-trip disappears entirely.
__global__ __launch_bounds__(256, 1)
void gaunt32_kernel(const float* __restrict__ feat,
                    const float* __restrict__ atype,
                    const float* __restrict__ wts,
                    float* __restrict__ out) {
  __shared__ uint4 TAB[2112];  // 33792 B: SYN frags [0,960), ANA frags [960,2112)

  const int tid = threadIdx.x;
  const int lane = tid & 63;
  const int m = lane & 31, h = lane >> 5;
  const int mtile = blockIdx.x * 4 + (tid >> 6);
  const int rowbase = mtile * 32;
  const int atom = mtile >> 2;         // 4 tiles per atom
  const int chb = (mtile & 3) * 32;    // channel base within atom

  // ---- stage constant tables: global -> LDS (L2-resident across blocks) ----
  {
    const uint4* s4 = reinterpret_cast<const uint4*>(SYNB.v);
    const uint4* a4 = reinterpret_cast<const uint4*>(ANAB.v);
#pragma unroll
    for (int i = 0; i < 4; ++i) {
      int idx = tid + 256 * i;
      if (idx < 960) TAB[idx] = s4[idx];
    }
#pragma unroll
    for (int i = 0; i < 5; ++i) {
      int idx = tid + 256 * i;
      if (idx < 1152) TAB[960 + idx] = a4[idx];
    }
  }

  const uint4* syn = TAB;        // frag (ks,nt): syn[(ks*5+nt)*64 + lane]
  const uint4* ana = TAB + 960;  // frag (ks,nt): ana[(ks*2+nt)*64 + lane]

  // ---- B-frag of c0^T straight from global (lane m holds row m's coeffs) ----
  const float* fr = feat + (size_t)(rowbase + m) * 36;
  S8 af[3];
  {
    float4 a = *reinterpret_cast<const float4*>(fr + h * 8);
    float4 b = *reinterpret_cast<const float4*>(fr + h * 8 + 4);
    af[0].u[0] = pk2(a.x, a.y); af[0].u[1] = pk2(a.z, a.w);
    af[0].u[2] = pk2(b.x, b.y); af[0].u[3] = pk2(b.z, b.w);
    a = *reinterpret_cast<const float4*>(fr + 16 + h * 8);
    b = *reinterpret_cast<const float4*>(fr + 20 + h * 8);
    af[1].u[0] = pk2(a.x, a.y); af[1].u[1] = pk2(a.z, a.w);
    af[1].u[2] = pk2(b.x, b.y); af[1].u[3] = pk2(b.z, b.w);
    af[2].u[0] = 0; af[2].u[1] = 0; af[2].u[2] = 0; af[2].u[3] = 0;
    if (h == 0) {  // k = 32..35 real; 36..47 zero (table rows >=36 are zero)
      a = *reinterpret_cast<const float4*>(fr + 32);
      af[2].u[0] = pk2(a.x, a.y); af[2].u[1] = pk2(a.z, a.w);
    }
  }

  // ---- wn[nu][l] for this lane's channel (atype row is wave-uniform) ----
  float wnv[3][6];
  {
    const float* ab = atype + atom * 10;
    float at_[10];
#pragma unroll
    for (int e = 0; e < 10; ++e) at_[e] = ab[e];
    const float* wb = wts + (size_t)(chb + m) * 6;
#pragma unroll
    for (int nu = 0; nu < 3; ++nu) {
#pragma unroll
      for (int l = 0; l < 6; ++l) wnv[nu][l] = 0.f;
#pragma unroll
      for (int e = 0; e < 10; ++e) {
        const float* p = wb + (size_t)(nu * 10 + e) * 768;
        float2 x = *reinterpret_cast<const float2*>(p);
        float2 y = *reinterpret_cast<const float2*>(p + 2);
        float2 z = *reinterpret_cast<const float2*>(p + 4);
        wnv[nu][0] += at_[e] * x.x; wnv[nu][1] += at_[e] * x.y;
        wnv[nu][2] += at_[e] * y.x; wnv[nu][3] += at_[e] * y.y;
        wnv[nu][4] += at_[e] * z.x; wnv[nu][5] += at_[e] * z.y;
      }
    }
  }

  // l-index of output col c = 8g+4h+i:  LC0t for h=0, LC1t for h=1.
  constexpr int LC0t[4][4] = {{0,1,1,1},{2,3,3,3},{4,4,4,4},{4,5,5,5}};  // l(8g+i)
  constexpr int LC1t[4][4] = {{2,2,2,2},{3,3,3,3},{4,4,4,4},{5,5,5,5}};  // l(8g+4+i)

  // ---- ovg/ov5 accumulators initialized with the w0*c0 term (fp32 c0) ----
  float ovg[4][4];
  float ov5[4];
  {
#pragma unroll
    for (int g = 0; g < 4; ++g) {
      float4 c = *reinterpret_cast<const float4*>(fr + 8 * g + 4 * h);
      const float* cp = reinterpret_cast<const float*>(&c);
#pragma unroll
      for (int i = 0; i < 4; ++i) {
        const float w0 = h ? wnv[0][LC1t[g][i]] : wnv[0][LC0t[g][i]];
        ovg[g][i] = w0 * cp[i];
      }
    }
    float4 c5 = {0.f, 0.f, 0.f, 0.f};
    if (h == 0) c5 = *reinterpret_cast<const float4*>(fr + 32);
    const float* cp = reinterpret_cast<const float*>(&c5);
#pragma unroll
    for (int i = 0; i < 4; ++i) ov5[i] = wnv[0][5] * cp[i];
  }
  // wnv[0] is now dead.

  __syncthreads();  // tables ready (once per block)

  // ---- phase A: GEMM1 (f^T = Y'^T c0^T) fused with g1 = f*f frag build and
  //      GEMM2 (prod1^T = Yw'^T g1^T), per grid-mtile ----
  f32x16 p1[2]; p1[0] = (f32x16)Z16; p1[1] = (f32x16)Z16;
#pragma unroll
  for (int mt = 0; mt < 5; ++mt) {
    f32x16 a1 = Z16;
#pragma unroll
    for (int ks = 0; ks < 3; ++ks)
      a1 = __builtin_amdgcn_mfma_f32_32x32x16_bf16(fr16(syn + (ks * 5 + mt) * 64 + lane),
                                                   af[ks].s, a1, 0, 0, 0);
#pragma unroll
    for (int q = 0; q < 2; ++q) {
      const int ksg = 2 * mt + q;
      if (ksg < 9) {
        S8 fb = mkfrag(pk2(a1[8*q+0]*a1[8*q+0], a1[8*q+1]*a1[8*q+1]),
                       pk2(a1[8*q+2]*a1[8*q+2], a1[8*q+3]*a1[8*q+3]),
                       pk2(a1[8*q+4]*a1[8*q+4], a1[8*q+5]*a1[8*q+5]),
                       pk2(a1[8*q+6]*a1[8*q+6], a1[8*q+7]*a1[8*q+7]));
        p1[0] = __builtin_amdgcn_mfma_f32_32x32x16_bf16(fr16(ana + (ksg * 2 + 0) * 64 + lane),
                                                        fb.s, p1[0], 0, 0, 0);
        p1[1] = __builtin_amdgcn_mfma_f32_32x32x16_bf16(fr16(ana + (ksg * 2 + 1) * 64 + lane),
                                                        fb.s, p1[1], 0, 0, 0);
      }
    }
  }

  // ---- fold w1*prod1 into ovg/ov5, then build b3 frags; p1 dies here ----
#pragma unroll
  for (int g = 0; g < 4; ++g)
#pragma unroll
    for (int i = 0; i < 4; ++i) {
      const float w1 = h ? wnv[1][LC1t[g][i]] : wnv[1][LC0t[g][i]];
      ovg[g][i] += w1 * p1[0][4 * g + i];
    }
#pragma unroll
  for (int i = 0; i < 4; ++i) ov5[i] += wnv[1][5] * p1[1][i];
  // wnv[1] dead; only wnv[2][0..5] stays live through phase B.

  // ---- B-frags of prod1^T (K=48; SH 36..47 are exact zeros from N-pad) ----
  S8 b3[3];
  b3[0] = mkfrag(pk2(p1[0][0],  p1[0][1]),  pk2(p1[0][2],  p1[0][3]),
                 pk2(p1[0][4],  p1[0][5]),  pk2(p1[0][6],  p1[0][7]));
  b3[1] = mkfrag(pk2(p1[0][8],  p1[0][9]),  pk2(p1[0][10], p1[0][11]),
                 pk2(p1[0][12], p1[0][13]), pk2(p1[0][14], p1[0][15]));
  b3[2] = mkfrag(pk2(p1[1][0],  p1[1][1]),  pk2(p1[1][2],  p1[1][3]),
                 pk2(p1[1][4],  p1[1][5]),  pk2(p1[1][6],  p1[1][7]));

  // ---- phase B: recompute f (GEMM1-bis) + GEMM3 (f2^T = Y'^T prod1^T),
  //      g2 = f2*f (both f32), GEMM4 (prod2^T = Yw'^T g2^T).
  //      Each SYN frag read feeds TWO MFMAs. ----
  f32x16 p2[2]; p2[0] = (f32x16)Z16; p2[1] = (f32x16)Z16;
#pragma unroll
  for (int mt = 0; mt < 5; ++mt) {
    f32x16 a1 = Z16, a3 = Z16;
#pragma unroll
    for (int ks = 0; ks < 3; ++ks) {
      short8 y = fr16(syn + (ks * 5 + mt) * 64 + lane);
      a1 = __builtin_amdgcn_mfma_f32_32x32x16_bf16(y, af[ks].s, a1, 0, 0, 0);
      a3 = __builtin_amdgcn_mfma_f32_32x32x16_bf16(y, b3[ks].s, a3, 0, 0, 0);
    }
#pragma unroll
    for (int q = 0; q < 2; ++q) {
      const int ksg = 2 * mt + q;
      if (ksg < 9) {
        S8 gb = mkfrag(pk2(a3[8*q+0]*a1[8*q+0], a3[8*q+1]*a1[8*q+1]),
                       pk2(a3[8*q+2]*a1[8*q+2], a3[8*q+3]*a1[8*q+3]),
                       pk2(a3[8*q+4]*a1[8*q+4], a3[8*q+5]*a1[8*q+5]),
                       pk2(a3[8*q+6]*a1[8*q+6], a3[8*q+7]*a1[8*q+7]));
        p2[0] = __builtin_amdgcn_mfma_f32_32x32x16_bf16(fr16(ana + (ksg * 2 + 0) * 64 + lane),
                                                        gb.s, p2[0], 0, 0, 0);
        p2[1] = __builtin_amdgcn_mfma_f32_32x32x16_bf16(fr16(ana + (ksg * 2 + 1) * 64 + lane),
                                                        gb.s, p2[1], 0, 0, 0);
      }
    }
  }

  // ---- final fold (w2*prod2) + store ----
  float* o0 = out + (size_t)(rowbase + m) * 36;
#pragma unroll
  for (int g = 0; g < 4; ++g) {
    float ov[4];
#pragma unroll
    for (int i = 0; i < 4; ++i) {
      const float w2 = h ? wnv[2][LC1t[g][i]] : wnv[2][LC0t[g][i]];
      ov[i] = ovg[g][i] + w2 * p2[0][4 * g + i];
    }
    float4 o4 = {ov[0], ov[1], ov[2], ov[3]};
    *reinterpret_cast<float4*>(o0 + 8 * g + 4 * h) = o4;
  }
  if (h == 0) {  // SH 32..35 (l=5), ntile-1 accumulator regs 0..3
    float ov[4];
#pragma unroll
    for (int i = 0; i < 4; ++i) ov[i] = ov5[i] + wnv[2][5] * p2[1][i];
    float4 o4 = {ov[0], ov[1], ov[2], ov[3]};
    *reinterpret_cast<float4*>(o0 + 32) = o4;
  }
}

extern "C" void kernel_launch(void* const* d_in, const int* in_sizes, int n_in,
                              void* d_out, int out_size, void* d_ws, size_t ws_size,
                              hipStream_t stream) {
  const float* feat = (const float*)d_in[0];   // [4096,128,36] f32
  const float* atype = (const float*)d_in[1];  // [4096,10] f32
  const float* wts = (const float*)d_in[2];    // [3,10,128,6] f32
  float* out = (float*)d_out;                  // [4096,128,36] f32
  (void)in_sizes; (void)n_in; (void)out_size; (void)d_ws; (void)ws_size;

  // 524288 rows / 32 per wave = 16384 tiles; 4 waves per block -> 4096 blocks.
  gaunt32_kernel<<<4096, 256, 0, stream>>>(feat, atype, wts, out);
}